// Round 3
// baseline (523.138 us; speedup 1.0000x reference)
//
#include <hip/hip_runtime.h>
#include <hip/hip_bf16.h>

#define NN 2000
#define EE 32000
#define TT 12
#define CIN 32
#define FCH 64
#define TB 96
#define NODE_F 3072   // TB*CIN floats per scrambled node
#define NODE_F4 768   // in float4

// workspace layout (float offsets)
#define OFF_X0    0
#define OFF_TX1   6144000
#define OFF_CHEB  12288000
#define OFF_DEG   24576000
#define OFF_SW    24578000
#define OFF_ROWP  24580000   // int[2048]
#define OFF_CNT   24582048   // int[2000]
#define OFF_FILL  24584048   // int[2000]
#define OFF_CCOL  24586048   // int[32000]
#define OFF_CW    24618048   // float[32000]
#define OFF_TWT   24650048   // ushort[12288] bf16 pre-transposed time_w [fc*3+j][ft]
#define OFF_RWT   24662336   // ushort[2048]  bf16 pre-transposed res_w  [c][ft]

__device__ __forceinline__ float comp4(const float4& v, int i) {
  return i == 0 ? v.x : (i == 1 ? v.y : (i == 2 ? v.z : v.w));
}

__device__ __forceinline__ float b2f(unsigned short u) {
  return __uint_as_float(((unsigned)u) << 16);
}

__device__ __forceinline__ unsigned short f2b(float x) {
  __hip_bfloat16 h = __float2bfloat16(x);   // RNE
  return *(unsigned short*)&h;
}

// ---- 0. pre-transpose conv weights to bf16 (once, tiny) ----
__global__ __launch_bounds__(256) void k_prep(const float* __restrict__ tw,
    const float* __restrict__ rw, unsigned short* __restrict__ twt,
    unsigned short* __restrict__ rwt) {
  int i = blockIdx.x * 256 + threadIdx.x;
  if (i < 12288) {
    int ft = i / 192;
    int r = i - ft * 192;
    twt[r * 64 + ft] = f2b(tw[i]);
  }
  if (i < 2048) {
    int ft = i >> 5;
    int c = i & 31;
    rwt[c * 64 + ft] = f2b(rw[i]);
  }
}

// ---- 1. degree (by src) and in-count (by dst) ----
__global__ __launch_bounds__(256) void k_deg_cnt(const int* __restrict__ src,
    const int* __restrict__ dst, const float* __restrict__ ew,
    float* __restrict__ deg, int* __restrict__ cnt) {
  int e = blockIdx.x * 256 + threadIdx.x;
  if (e < EE) {
    atomicAdd(&deg[src[e]], ew[e]);
    atomicAdd(&cnt[dst[e]], 1);
  }
}

// ---- 2. self-loop weights + exclusive scan of cnt -> rowptr ----
__global__ __launch_bounds__(256) void k_scan(const float* __restrict__ deg,
    const float* __restrict__ lam, const int* __restrict__ cnt,
    float* __restrict__ sw, int* __restrict__ rowp) {
  int tid = threadIdx.x;
  float s = 2.0f / lam[0];
  for (int n = tid; n < NN; n += 256) sw[n] = deg[n] * s - 1.0f;
  __shared__ int part[256];
  int base = tid * 8;
  int local[8];
  int sum = 0;
  #pragma unroll
  for (int i = 0; i < 8; ++i) {
    int idx = base + i;
    int v = (idx < NN) ? cnt[idx] : 0;
    local[i] = sum;
    sum += v;
  }
  part[tid] = sum;
  __syncthreads();
  for (int off = 1; off < 256; off <<= 1) {
    int v = part[tid];
    int add = (tid >= off) ? part[tid - off] : 0;
    __syncthreads();
    part[tid] = v + add;
    __syncthreads();
  }
  int excl = part[tid] - sum;  // exclusive prefix of this chunk
  #pragma unroll
  for (int i = 0; i < 8; ++i) {
    int idx = base + i;
    if (idx < NN) rowp[idx] = excl + local[i];
  }
  if (tid == 255) rowp[NN] = part[255];
}

// ---- 3. CSR fill (rows = dst). w_e = -2*ew/lam - [src==dst] ----
__global__ __launch_bounds__(256) void k_fill(const int* __restrict__ src,
    const int* __restrict__ dst, const float* __restrict__ ew,
    const float* __restrict__ lam, const int* __restrict__ rowp,
    int* __restrict__ fill, int* __restrict__ ccol, float* __restrict__ cw) {
  int e = blockIdx.x * 256 + threadIdx.x;
  if (e < EE) {
    float s = 2.0f / lam[0];
    int d = dst[e], sn = src[e];
    int pos = rowp[d] + atomicAdd(&fill[d], 1);
    ccol[pos] = sn;
    cw[pos] = -ew[e] * s - ((sn == d) ? 1.0f : 0.0f);
  }
}

// ---- 4. build scrambled x0 [N][q=96][c=32] ----
__global__ __launch_bounds__(256) void k_build_x0(const float* __restrict__ X,
                                                  float* __restrict__ x0) {
  int o = blockIdx.x * 256 + threadIdx.x;
  if (o >= NN * NODE_F) return;
  int n = o / NODE_F;
  int rem = o - n * NODE_F;
  int q = rem >> 5;
  int c2 = rem & 31;
  // flat index into (C,B,N,T)-contiguous view of X
  int g = n * NODE_F + c2 * TB + q;
  int ci = g / 192000;            // C stride = B*N*T
  int r1 = g - ci * 192000;
  int b = r1 / 24000;             // N*T
  int r2 = r1 - b * 24000;
  int nn2 = r2 / 12;
  int t = r2 - nn2 * 12;
  x0[o] = X[((b * NN + nn2) * CIN + ci) * TT + t];
}

// ---- 5. Tx1 = L_hat @ x0 (block per node, 12 floats/thread) ----
__global__ __launch_bounds__(256) void k_prop1(const float* __restrict__ x0,
    const float* __restrict__ sw, const int* __restrict__ rowp,
    const int* __restrict__ ccol, const float* __restrict__ cw,
    float* __restrict__ tx1) {
  int n = blockIdx.x, tid = threadIdx.x;
  float s = sw[n];
  const float4* xb = (const float4*)x0;
  int own = n * NODE_F4 + tid * 3;
  float4 v0 = xb[own], v1 = xb[own + 1], v2 = xb[own + 2];
  float a[12];
  a[0]=s*v0.x; a[1]=s*v0.y; a[2]=s*v0.z; a[3]=s*v0.w;
  a[4]=s*v1.x; a[5]=s*v1.y; a[6]=s*v1.z; a[7]=s*v1.w;
  a[8]=s*v2.x; a[9]=s*v2.y; a[10]=s*v2.z; a[11]=s*v2.w;
  int rs = rowp[n], re = rowp[n + 1];
  for (int e = rs; e < re; ++e) {
    int c = ccol[e];
    float w = cw[e];
    int cb = c * NODE_F4 + tid * 3;
    float4 u0 = xb[cb], u1 = xb[cb + 1], u2 = xb[cb + 2];
    a[0]+=w*u0.x; a[1]+=w*u0.y; a[2]+=w*u0.z; a[3]+=w*u0.w;
    a[4]+=w*u1.x; a[5]+=w*u1.y; a[6]+=w*u1.z; a[7]+=w*u1.w;
    a[8]+=w*u2.x; a[9]+=w*u2.y; a[10]+=w*u2.z; a[11]+=w*u2.w;
  }
  float4* ob = (float4*)tx1;
  float4 o0, o1, o2;
  o0.x=a[0]; o0.y=a[1]; o0.z=a[2]; o0.w=a[3];
  o1.x=a[4]; o1.y=a[5]; o1.z=a[6]; o1.w=a[7];
  o2.x=a[8]; o2.y=a[9]; o2.z=a[10]; o2.w=a[11];
  ob[own] = o0; ob[own + 1] = o1; ob[own + 2] = o2;
}

// ---- 6. Tx2 = 2*L_hat@Tx1 - x0 ; cheb = relu(x0@W0 + Tx1@W1 + Tx2@W2 + b) ----
__global__ __launch_bounds__(256) void k_cheb(const float* __restrict__ x0,
    const float* __restrict__ tx1, const float* __restrict__ sw,
    const int* __restrict__ rowp, const int* __restrict__ ccol,
    const float* __restrict__ cw, const float* __restrict__ Wc,
    const float* __restrict__ bc, float* __restrict__ cheb) {
  __shared__ float x0l[NODE_F];
  __shared__ float t1l[NODE_F];
  __shared__ float t2l[NODE_F];
  __shared__ __align__(16) unsigned short wl[3 * 2048];  // bf16 weights, 12 KB
  __shared__ float bl[64];
  int n = blockIdx.x, tid = threadIdx.x;
  {
    const float4* xs = (const float4*)(x0 + (size_t)n * NODE_F);
    const float4* ts = (const float4*)(tx1 + (size_t)n * NODE_F);
    float4* xd = (float4*)x0l;
    float4* td = (float4*)t1l;
    for (int i = tid; i < NODE_F4; i += 256) { xd[i] = xs[i]; td[i] = ts[i]; }
    for (int i = tid; i < 6144; i += 256) wl[i] = f2b(Wc[i]);
    if (tid < 64) bl[tid] = bc[tid];
  }
  // edge accumulation on own 12 elements (from global tx1; LDS not ready yet)
  float s = sw[n];
  float a[12];
  {
    const float4* tg4 = (const float4*)tx1 + (size_t)n * NODE_F4 + tid * 3;
    float4 v0 = tg4[0], v1 = tg4[1], v2 = tg4[2];
    a[0]=s*v0.x; a[1]=s*v0.y; a[2]=s*v0.z; a[3]=s*v0.w;
    a[4]=s*v1.x; a[5]=s*v1.y; a[6]=s*v1.z; a[7]=s*v1.w;
    a[8]=s*v2.x; a[9]=s*v2.y; a[10]=s*v2.z; a[11]=s*v2.w;
  }
  int rs = rowp[n], re = rowp[n + 1];
  const float4* xb = (const float4*)tx1;
  for (int e = rs; e < re; ++e) {
    int c = ccol[e];
    float w = cw[e];
    int cb = c * NODE_F4 + tid * 3;
    float4 u0 = xb[cb], u1 = xb[cb + 1], u2 = xb[cb + 2];
    a[0]+=w*u0.x; a[1]+=w*u0.y; a[2]+=w*u0.z; a[3]+=w*u0.w;
    a[4]+=w*u1.x; a[5]+=w*u1.y; a[6]+=w*u1.z; a[7]+=w*u1.w;
    a[8]+=w*u2.x; a[9]+=w*u2.y; a[10]+=w*u2.z; a[11]+=w*u2.w;
  }
  __syncthreads();   // staging complete; safe to read x0l and write t2l
  #pragma unroll
  for (int j = 0; j < 12; ++j) t2l[tid * 12 + j] = 2.0f * a[j] - x0l[tid * 12 + j];
  __syncthreads();
  // einsum: thread (qg = tid>>6, f = tid&63) computes q = qi*4+qg, qi<24
  int f = tid & 63, qg = tid >> 6;
  float o[24];
  #pragma unroll
  for (int qi = 0; qi < 24; ++qi) o[qi] = bl[f];
  for (int cc = 0; cc < 4; ++cc) {
    float w0r[8], w1r[8], w2r[8];
    #pragma unroll
    for (int i = 0; i < 8; ++i) {
      int c = cc * 8 + i;
      w0r[i] = b2f(wl[c * 64 + f]);
      w1r[i] = b2f(wl[2048 + c * 64 + f]);
      w2r[i] = b2f(wl[4096 + c * 64 + f]);
    }
    #pragma unroll
    for (int qi = 0; qi < 24; ++qi) {
      int q = qi * 4 + qg;
      const float* xr = &x0l[q * 32 + cc * 8];
      const float* t1r = &t1l[q * 32 + cc * 8];
      const float* t2r = &t2l[q * 32 + cc * 8];
      float4 xv0 = *(const float4*)(xr);
      float4 xv1 = *(const float4*)(xr + 4);
      float4 y0 = *(const float4*)(t1r);
      float4 y1 = *(const float4*)(t1r + 4);
      float4 z0 = *(const float4*)(t2r);
      float4 z1 = *(const float4*)(t2r + 4);
      float acc = o[qi];
      #pragma unroll
      for (int i = 0; i < 4; ++i) {
        acc += comp4(xv0, i) * w0r[i] + comp4(y0, i) * w1r[i] + comp4(z0, i) * w2r[i];
        acc += comp4(xv1, i) * w0r[i + 4] + comp4(y1, i) * w1r[i + 4] + comp4(z1, i) * w2r[i + 4];
      }
      o[qi] = acc;
    }
  }
  float* cp = cheb + (size_t)n * TB * FCH;
  #pragma unroll
  for (int qi = 0; qi < 24; ++qi) {
    int q = qi * 4 + qg;
    cp[q * 64 + f] = fmaxf(o[qi], 0.0f);
  }
}

// ---- 7. temporal conv + residual + relu + layernorm(F) + output transpose ----
// 768 blocks grid-stride over 4000 groups of 4 (b,n) pairs (wave per pair,
// lane = f). bf16 weights in LDS -> 43 KB/block -> 3 blocks/CU.
__global__ __launch_bounds__(256, 4) void k_final2(const float* __restrict__ X,
    const float* __restrict__ cheb, const unsigned short* __restrict__ twt,
    const unsigned short* __restrict__ rwt, const float* __restrict__ tb,
    const float* __restrict__ rb, const float* __restrict__ lg,
    const float* __restrict__ lb, float* __restrict__ out) {
  __shared__ __align__(16) unsigned short twl[12288];  // bf16 [(fc*3+j)][ft], 24 KB
  __shared__ __align__(16) unsigned short rwl[2048];   // bf16 [c][ft], 4 KB
  __shared__ float chl[4 * 896];    // per-wave slice: [t+1][fc] rows 0,13 zero; reused as zl
  int tid = threadIdx.x;
  int nt = tid >> 6;
  int f = tid & 63;
  {
    const float4* s4 = (const float4*)twt;   // 24576 B = 1536 float4
    float4* d4 = (float4*)twl;
    for (int i = tid; i < 1536; i += 256) d4[i] = s4[i];
    const float4* r4 = (const float4*)rwt;   // 4096 B = 256 float4
    float4* e4 = (float4*)rwl;
    for (int i = tid; i < 256; i += 256) e4[i] = r4[i];
  }
  float tbf = tb[f], rbf = rb[f], lgf = lg[f], lbf = lb[f];
  __syncthreads();
  float* ch = &chl[nt * 896];
  for (int g = blockIdx.x; g < 4000; g += 768) {
    int p = g * 4 + nt;          // pair index = b*2000 + n (2000 % 4 == 0)
    int b = p / 2000;
    int n = p - b * 2000;
    // stage this wave's cheb rows [12][64] into ch rows 1..12; zero-pad rows 0,13
    {
      const float4* src = (const float4*)(cheb + ((size_t)n * TB + b * TT) * FCH);
      float4* dst = (float4*)(ch + 64);
      #pragma unroll
      for (int i = 0; i < 3; ++i) dst[f + i * 64] = src[f + i * 64];
      ch[f] = 0.0f;
      ch[13 * 64 + f] = 0.0f;
    }
    // temporal conv: h[t] = tb[f] + sum_fc sum_j tw[f][fc][j] * ch[t+j][fc]
    float h[12];
    #pragma unroll
    for (int t = 0; t < 12; ++t) h[t] = tbf;
    for (int fc4 = 0; fc4 < 16; ++fc4) {
      float4 ck[14];
      #pragma unroll
      for (int k = 0; k < 14; ++k) ck[k] = *(const float4*)(ch + k * 64 + fc4 * 4);
      #pragma unroll
      for (int i = 0; i < 4; ++i) {
        int fc = fc4 * 4 + i;
        float w0 = b2f(twl[(fc * 3 + 0) * 64 + f]);
        float w1 = b2f(twl[(fc * 3 + 1) * 64 + f]);
        float w2 = b2f(twl[(fc * 3 + 2) * 64 + f]);
        #pragma unroll
        for (int t = 0; t < 12; ++t)
          h[t] += w0 * comp4(ck[t], i) + w1 * comp4(ck[t + 1], i) + w2 * comp4(ck[t + 2], i);
      }
    }
    // residual 1x1 conv on raw X (wave-uniform broadcast loads)
    float r[12];
    #pragma unroll
    for (int t = 0; t < 12; ++t) r[t] = rbf;
    const float* xp = X + (size_t)p * 384;
    #pragma unroll
    for (int c = 0; c < 32; ++c) {
      float4 xa = *(const float4*)(xp + c * 12);
      float4 xbv = *(const float4*)(xp + c * 12 + 4);
      float4 xc = *(const float4*)(xp + c * 12 + 8);
      float wv = b2f(rwl[c * 64 + f]);
      r[0] += wv * xa.x; r[1] += wv * xa.y; r[2] += wv * xa.z; r[3] += wv * xa.w;
      r[4] += wv * xbv.x; r[5] += wv * xbv.y; r[6] += wv * xbv.z; r[7] += wv * xbv.w;
      r[8] += wv * xc.x; r[9] += wv * xc.y; r[10] += wv * xc.z; r[11] += wv * xc.w;
    }
    // relu + layernorm over f (64 lanes = one wave); write zl into own slice
    #pragma unroll
    for (int t = 0; t < 12; ++t) {
      float zz = fmaxf(h[t] + r[t], 0.0f);
      float sum = zz, sq = zz * zz;
      #pragma unroll
      for (int off = 32; off; off >>= 1) {
        sum += __shfl_xor(sum, off);
        sq += __shfl_xor(sq, off);
      }
      float mu = sum * (1.0f / 64.0f);
      float var = sq * (1.0f / 64.0f) - mu * mu;
      float inv = rsqrtf(var + 1e-5f);
      ch[f * 13 + t] = (zz - mu) * inv * lgf + lbf;   // zl[f][t]
    }
    // per-wave coalesced store: out[b][n][f][t] = 768 consecutive floats
    float* op = out + (size_t)p * 768;
    #pragma unroll
    for (int k = 0; k < 12; ++k) {
      int i = f + k * 64;
      op[i] = ch[(i / 12) * 13 + i % 12];
    }
  }
}

extern "C" void kernel_launch(void* const* d_in, const int* in_sizes, int n_in,
                              void* d_out, int out_size, void* d_ws, size_t ws_size,
                              hipStream_t stream) {
  const float* X   = (const float*)d_in[0];
  const int*   ei  = (const int*)d_in[1];
  const float* ew  = (const float*)d_in[2];
  const float* lam = (const float*)d_in[3];
  const float* Wc  = (const float*)d_in[4];
  const float* bc  = (const float*)d_in[5];
  const float* tw  = (const float*)d_in[6];
  const float* tb  = (const float*)d_in[7];
  const float* rw  = (const float*)d_in[8];
  const float* rb  = (const float*)d_in[9];
  const float* lg  = (const float*)d_in[10];
  const float* lb  = (const float*)d_in[11];
  float* out = (float*)d_out;
  float* ws = (float*)d_ws;
  float* x0   = ws + OFF_X0;
  float* tx1  = ws + OFF_TX1;
  float* cheb = ws + OFF_CHEB;
  float* deg  = ws + OFF_DEG;
  float* swv  = ws + OFF_SW;
  int* rowp = (int*)(ws + OFF_ROWP);
  int* cnt  = (int*)(ws + OFF_CNT);
  int* fill = (int*)(ws + OFF_FILL);
  int* ccol = (int*)(ws + OFF_CCOL);
  float* cwv = ws + OFF_CW;
  unsigned short* twt = (unsigned short*)(ws + OFF_TWT);
  unsigned short* rwt = (unsigned short*)(ws + OFF_RWT);
  const int* srcp = ei;
  const int* dstp = ei + EE;

  hipMemsetAsync(deg, 0, (size_t)(OFF_CCOL - OFF_DEG) * sizeof(float), stream);
  k_prep<<<48, 256, 0, stream>>>(tw, rw, twt, rwt);
  k_deg_cnt<<<(EE + 255) / 256, 256, 0, stream>>>(srcp, dstp, ew, deg, cnt);
  k_scan<<<1, 256, 0, stream>>>(deg, lam, cnt, swv, rowp);
  k_fill<<<(EE + 255) / 256, 256, 0, stream>>>(srcp, dstp, ew, lam, rowp, fill, ccol, cwv);
  k_build_x0<<<(NN * NODE_F + 255) / 256, 256, 0, stream>>>(X, x0);
  k_prop1<<<NN, 256, 0, stream>>>(x0, swv, rowp, ccol, cwv, tx1);
  k_cheb<<<NN, 256, 0, stream>>>(x0, tx1, swv, rowp, ccol, cwv, Wc, bc, cheb);
  k_final2<<<768, 256, 0, stream>>>(X, cheb, twt, rwt, tb, rb, lg, lb, out);
}

// Round 4
// 407.010 us; speedup vs baseline: 1.2853x; 1.2853x over previous
//
#include <hip/hip_runtime.h>
#include <hip/hip_bf16.h>

#define NN 2000
#define EE 32000
#define TT 12
#define CIN 32
#define FCH 64
#define TB 96
#define NODE_F 3072   // TB*CIN floats per scrambled node
#define NODE_F4 768   // in float4

// workspace layout (float offsets)
#define OFF_X0    0
#define OFF_TX1   6144000
#define OFF_CHEB  12288000
#define OFF_DEG   24576000
#define OFF_SW    24578000
#define OFF_ROWP  24580000   // int[2048]
#define OFF_CNT   24582048   // int[2000]
#define OFF_FILL  24584048   // int[2000]
#define OFF_CCOL  24586048   // int[32000]
#define OFF_CW    24618048   // float[32000]
#define OFF_TWT   24650048   // ushort[12288] bf16 pre-transposed time_w [fc*3+j][ft]
#define OFF_RWT   24662336   // ushort[2048]  bf16 pre-transposed res_w  [c][ft]

__device__ __forceinline__ float comp4(const float4& v, int i) {
  return i == 0 ? v.x : (i == 1 ? v.y : (i == 2 ? v.z : v.w));
}

__device__ __forceinline__ float b2f(unsigned short u) {
  return __uint_as_float(((unsigned)u) << 16);
}

__device__ __forceinline__ unsigned short f2b(float x) {
  __hip_bfloat16 h = __float2bfloat16(x);   // RNE
  return *(unsigned short*)&h;
}

// ---- 0. pre-transpose conv weights to bf16 (once, tiny) ----
__global__ __launch_bounds__(256) void k_prep(const float* __restrict__ tw,
    const float* __restrict__ rw, unsigned short* __restrict__ twt,
    unsigned short* __restrict__ rwt) {
  int i = blockIdx.x * 256 + threadIdx.x;
  if (i < 12288) {
    int ft = i / 192;
    int r = i - ft * 192;
    twt[r * 64 + ft] = f2b(tw[i]);
  }
  if (i < 2048) {
    int ft = i >> 5;
    int c = i & 31;
    rwt[c * 64 + ft] = f2b(rw[i]);
  }
}

// ---- 1. degree (by src) and in-count (by dst) ----
__global__ __launch_bounds__(256) void k_deg_cnt(const int* __restrict__ src,
    const int* __restrict__ dst, const float* __restrict__ ew,
    float* __restrict__ deg, int* __restrict__ cnt) {
  int e = blockIdx.x * 256 + threadIdx.x;
  if (e < EE) {
    atomicAdd(&deg[src[e]], ew[e]);
    atomicAdd(&cnt[dst[e]], 1);
  }
}

// ---- 2. self-loop weights + exclusive scan of cnt -> rowptr ----
__global__ __launch_bounds__(256) void k_scan(const float* __restrict__ deg,
    const float* __restrict__ lam, const int* __restrict__ cnt,
    float* __restrict__ sw, int* __restrict__ rowp) {
  int tid = threadIdx.x;
  float s = 2.0f / lam[0];
  for (int n = tid; n < NN; n += 256) sw[n] = deg[n] * s - 1.0f;
  __shared__ int part[256];
  int base = tid * 8;
  int local[8];
  int sum = 0;
  #pragma unroll
  for (int i = 0; i < 8; ++i) {
    int idx = base + i;
    int v = (idx < NN) ? cnt[idx] : 0;
    local[i] = sum;
    sum += v;
  }
  part[tid] = sum;
  __syncthreads();
  for (int off = 1; off < 256; off <<= 1) {
    int v = part[tid];
    int add = (tid >= off) ? part[tid - off] : 0;
    __syncthreads();
    part[tid] = v + add;
    __syncthreads();
  }
  int excl = part[tid] - sum;  // exclusive prefix of this chunk
  #pragma unroll
  for (int i = 0; i < 8; ++i) {
    int idx = base + i;
    if (idx < NN) rowp[idx] = excl + local[i];
  }
  if (tid == 255) rowp[NN] = part[255];
}

// ---- 3. CSR fill (rows = dst). w_e = -2*ew/lam - [src==dst] ----
__global__ __launch_bounds__(256) void k_fill(const int* __restrict__ src,
    const int* __restrict__ dst, const float* __restrict__ ew,
    const float* __restrict__ lam, const int* __restrict__ rowp,
    int* __restrict__ fill, int* __restrict__ ccol, float* __restrict__ cw) {
  int e = blockIdx.x * 256 + threadIdx.x;
  if (e < EE) {
    float s = 2.0f / lam[0];
    int d = dst[e], sn = src[e];
    int pos = rowp[d] + atomicAdd(&fill[d], 1);
    ccol[pos] = sn;
    cw[pos] = -ew[e] * s - ((sn == d) ? 1.0f : 0.0f);
  }
}

// ---- 4. build scrambled x0 [N][q=96][c=32] ----
__global__ __launch_bounds__(256) void k_build_x0(const float* __restrict__ X,
                                                  float* __restrict__ x0) {
  int o = blockIdx.x * 256 + threadIdx.x;
  if (o >= NN * NODE_F) return;
  int n = o / NODE_F;
  int rem = o - n * NODE_F;
  int q = rem >> 5;
  int c2 = rem & 31;
  // flat index into (C,B,N,T)-contiguous view of X
  int g = n * NODE_F + c2 * TB + q;
  int ci = g / 192000;            // C stride = B*N*T
  int r1 = g - ci * 192000;
  int b = r1 / 24000;             // N*T
  int r2 = r1 - b * 24000;
  int nn2 = r2 / 12;
  int t = r2 - nn2 * 12;
  x0[o] = X[((b * NN + nn2) * CIN + ci) * TT + t];
}

// ---- 5. Tx1 = L_hat @ x0 (block per node, 12 floats/thread) ----
__global__ __launch_bounds__(256) void k_prop1(const float* __restrict__ x0,
    const float* __restrict__ sw, const int* __restrict__ rowp,
    const int* __restrict__ ccol, const float* __restrict__ cw,
    float* __restrict__ tx1) {
  int n = blockIdx.x, tid = threadIdx.x;
  float s = sw[n];
  const float4* xb = (const float4*)x0;
  int own = n * NODE_F4 + tid * 3;
  float4 v0 = xb[own], v1 = xb[own + 1], v2 = xb[own + 2];
  float a[12];
  a[0]=s*v0.x; a[1]=s*v0.y; a[2]=s*v0.z; a[3]=s*v0.w;
  a[4]=s*v1.x; a[5]=s*v1.y; a[6]=s*v1.z; a[7]=s*v1.w;
  a[8]=s*v2.x; a[9]=s*v2.y; a[10]=s*v2.z; a[11]=s*v2.w;
  int rs = rowp[n], re = rowp[n + 1];
  for (int e = rs; e < re; ++e) {
    int c = ccol[e];
    float w = cw[e];
    int cb = c * NODE_F4 + tid * 3;
    float4 u0 = xb[cb], u1 = xb[cb + 1], u2 = xb[cb + 2];
    a[0]+=w*u0.x; a[1]+=w*u0.y; a[2]+=w*u0.z; a[3]+=w*u0.w;
    a[4]+=w*u1.x; a[5]+=w*u1.y; a[6]+=w*u1.z; a[7]+=w*u1.w;
    a[8]+=w*u2.x; a[9]+=w*u2.y; a[10]+=w*u2.z; a[11]+=w*u2.w;
  }
  float4* ob = (float4*)tx1;
  float4 o0, o1, o2;
  o0.x=a[0]; o0.y=a[1]; o0.z=a[2]; o0.w=a[3];
  o1.x=a[4]; o1.y=a[5]; o1.z=a[6]; o1.w=a[7];
  o2.x=a[8]; o2.y=a[9]; o2.z=a[10]; o2.w=a[11];
  ob[own] = o0; ob[own + 1] = o1; ob[own + 2] = o2;
}

// ---- 6. Tx2 = 2*L_hat@Tx1 - x0 ; cheb = relu(x0@W0 + Tx1@W1 + Tx2@W2 + b) ----
__global__ __launch_bounds__(256) void k_cheb(const float* __restrict__ x0,
    const float* __restrict__ tx1, const float* __restrict__ sw,
    const int* __restrict__ rowp, const int* __restrict__ ccol,
    const float* __restrict__ cw, const float* __restrict__ Wc,
    const float* __restrict__ bc, float* __restrict__ cheb) {
  __shared__ float x0l[NODE_F];
  __shared__ float t1l[NODE_F];
  __shared__ float t2l[NODE_F];
  __shared__ __align__(16) unsigned short wl[3 * 2048];  // bf16 weights, 12 KB
  __shared__ float bl[64];
  int n = blockIdx.x, tid = threadIdx.x;
  {
    const float4* xs = (const float4*)(x0 + (size_t)n * NODE_F);
    const float4* ts = (const float4*)(tx1 + (size_t)n * NODE_F);
    float4* xd = (float4*)x0l;
    float4* td = (float4*)t1l;
    for (int i = tid; i < NODE_F4; i += 256) { xd[i] = xs[i]; td[i] = ts[i]; }
    for (int i = tid; i < 6144; i += 256) wl[i] = f2b(Wc[i]);
    if (tid < 64) bl[tid] = bc[tid];
  }
  // edge accumulation on own 12 elements (from global tx1; LDS not ready yet)
  float s = sw[n];
  float a[12];
  {
    const float4* tg4 = (const float4*)tx1 + (size_t)n * NODE_F4 + tid * 3;
    float4 v0 = tg4[0], v1 = tg4[1], v2 = tg4[2];
    a[0]=s*v0.x; a[1]=s*v0.y; a[2]=s*v0.z; a[3]=s*v0.w;
    a[4]=s*v1.x; a[5]=s*v1.y; a[6]=s*v1.z; a[7]=s*v1.w;
    a[8]=s*v2.x; a[9]=s*v2.y; a[10]=s*v2.z; a[11]=s*v2.w;
  }
  int rs = rowp[n], re = rowp[n + 1];
  const float4* xb = (const float4*)tx1;
  for (int e = rs; e < re; ++e) {
    int c = ccol[e];
    float w = cw[e];
    int cb = c * NODE_F4 + tid * 3;
    float4 u0 = xb[cb], u1 = xb[cb + 1], u2 = xb[cb + 2];
    a[0]+=w*u0.x; a[1]+=w*u0.y; a[2]+=w*u0.z; a[3]+=w*u0.w;
    a[4]+=w*u1.x; a[5]+=w*u1.y; a[6]+=w*u1.z; a[7]+=w*u1.w;
    a[8]+=w*u2.x; a[9]+=w*u2.y; a[10]+=w*u2.z; a[11]+=w*u2.w;
  }
  __syncthreads();   // staging complete; safe to read x0l and write t2l
  #pragma unroll
  for (int j = 0; j < 12; ++j) t2l[tid * 12 + j] = 2.0f * a[j] - x0l[tid * 12 + j];
  __syncthreads();
  // einsum: thread (qg = tid>>6, f = tid&63) computes q = qi*4+qg, qi<24
  int f = tid & 63, qg = tid >> 6;
  float o[24];
  #pragma unroll
  for (int qi = 0; qi < 24; ++qi) o[qi] = bl[f];
  for (int cc = 0; cc < 4; ++cc) {
    float w0r[8], w1r[8], w2r[8];
    #pragma unroll
    for (int i = 0; i < 8; ++i) {
      int c = cc * 8 + i;
      w0r[i] = b2f(wl[c * 64 + f]);
      w1r[i] = b2f(wl[2048 + c * 64 + f]);
      w2r[i] = b2f(wl[4096 + c * 64 + f]);
    }
    #pragma unroll
    for (int qi = 0; qi < 24; ++qi) {
      int q = qi * 4 + qg;
      const float* xr = &x0l[q * 32 + cc * 8];
      const float* t1r = &t1l[q * 32 + cc * 8];
      const float* t2r = &t2l[q * 32 + cc * 8];
      float4 xv0 = *(const float4*)(xr);
      float4 xv1 = *(const float4*)(xr + 4);
      float4 y0 = *(const float4*)(t1r);
      float4 y1 = *(const float4*)(t1r + 4);
      float4 z0 = *(const float4*)(t2r);
      float4 z1 = *(const float4*)(t2r + 4);
      float acc = o[qi];
      #pragma unroll
      for (int i = 0; i < 4; ++i) {
        acc += comp4(xv0, i) * w0r[i] + comp4(y0, i) * w1r[i] + comp4(z0, i) * w2r[i];
        acc += comp4(xv1, i) * w0r[i + 4] + comp4(y1, i) * w1r[i + 4] + comp4(z1, i) * w2r[i + 4];
      }
      o[qi] = acc;
    }
  }
  float* cp = cheb + (size_t)n * TB * FCH;
  #pragma unroll
  for (int qi = 0; qi < 24; ++qi) {
    int q = qi * 4 + qg;
    cp[q * 64 + f] = fmaxf(o[qi], 0.0f);
  }
}

// ---- 7. temporal conv + residual + relu + layernorm(F) + output transpose ----
// Block = 4 waves cooperating on ONE (b,n) pair; 16 sequential pairs/block.
// Wave w owns fc in [16w,16w+16) and c in [8w,8w+8): weights live in VGPRs
// (loaded once). Conv/residual data is wave-uniform -> scalar-path loads
// (uniform pointer via readfirstlane). Partials reduced through 12 KB LDS.
__global__ __launch_bounds__(256, 4) void k_final3(const float* __restrict__ X,
    const float* __restrict__ cheb, const unsigned short* __restrict__ twt,
    const unsigned short* __restrict__ rwt, const float* __restrict__ tb,
    const float* __restrict__ rb, const float* __restrict__ lg,
    const float* __restrict__ lb, float* __restrict__ out) {
  __shared__ float hp[4 * 12 * 64];   // partial h per wave
  __shared__ float zb[64 * 13];       // normalized z, [f][13] padded
  int tid = threadIdx.x;
  int f = tid & 63;
  int ntu = __builtin_amdgcn_readfirstlane(tid >> 6);  // wave id, provably uniform

  // per-lane weights in VGPRs (loaded once; coalesced over f)
  float w0[16], w1[16], w2[16];
  #pragma unroll
  for (int i = 0; i < 16; ++i) {
    int fc = ntu * 16 + i;
    w0[i] = b2f(twt[(fc * 3 + 0) * 64 + f]);
    w1[i] = b2f(twt[(fc * 3 + 1) * 64 + f]);
    w2[i] = b2f(twt[(fc * 3 + 2) * 64 + f]);
  }
  float rwv[8];
  #pragma unroll
  for (int i = 0; i < 8; ++i) rwv[i] = b2f(rwt[(ntu * 8 + i) * 64 + f]);
  float tbf = tb[f], rbf = rb[f], lgf = lg[f], lbf = lb[f];
  float hbase = (ntu == 0) ? (tbf + rbf) : 0.0f;

  for (int it = 0; it < 16; ++it) {
    int p = blockIdx.x * 16 + it;      // uniform pair index = b*2000 + n
    int b = p / 2000;
    int n = p - b * 2000;
    float h[12];
    #pragma unroll
    for (int t = 0; t < 12; ++t) h[t] = hbase;
    // temporal conv partial over this wave's 16 fc (scalar-path reads)
    {
      const float4* ch4 = (const float4*)(cheb + (size_t)n * 6144 + b * 768 + ntu * 16);
      #pragma unroll
      for (int r = 0; r < 12; ++r) {
        float4 sa = ch4[r * 16 + 0];
        float4 sb = ch4[r * 16 + 1];
        float4 sc = ch4[r * 16 + 2];
        float4 sd = ch4[r * 16 + 3];
        #pragma unroll
        for (int i = 0; i < 16; ++i) {
          float v = (i < 4) ? comp4(sa, i) : (i < 8) ? comp4(sb, i - 4)
                  : (i < 12) ? comp4(sc, i - 8) : comp4(sd, i - 12);
          if (r <= 10) h[r + 1] += w0[i] * v;
          h[r] += w1[i] * v;
          if (r >= 1) h[r - 1] += w2[i] * v;
        }
      }
    }
    // residual partial over this wave's 8 channels (scalar-path reads)
    {
      const float4* xp4 = (const float4*)(X + (size_t)p * 384 + ntu * 96);
      #pragma unroll
      for (int ci = 0; ci < 24; ++ci) {
        float4 xv = xp4[ci];
        #pragma unroll
        for (int k = 0; k < 4; ++k) {
          int idx = ci * 4 + k;            // 0..95, static
          h[idx % 12] += rwv[idx / 12] * comp4(xv, k);
        }
      }
    }
    // write partials, reduce, LN
    #pragma unroll
    for (int t = 0; t < 12; ++t) hp[ntu * 768 + t * 64 + f] = h[t];
    __syncthreads();
    #pragma unroll
    for (int tt = 0; tt < 3; ++tt) {
      int t = ntu * 3 + tt;
      float v = hp[t * 64 + f] + hp[768 + t * 64 + f]
              + hp[1536 + t * 64 + f] + hp[2304 + t * 64 + f];
      v = fmaxf(v, 0.0f);
      float sum = v, sq = v * v;
      #pragma unroll
      for (int off = 32; off; off >>= 1) {
        sum += __shfl_xor(sum, off);
        sq += __shfl_xor(sq, off);
      }
      float mu = sum * (1.0f / 64.0f);
      float var = sq * (1.0f / 64.0f) - mu * mu;
      float inv = rsqrtf(var + 1e-5f);
      zb[f * 13 + t] = (v - mu) * inv * lgf + lbf;
    }
    __syncthreads();
    // coalesced store: out[p][f][t] = 768 consecutive floats
    float* op = out + (size_t)p * 768;
    #pragma unroll
    for (int k = 0; k < 3; ++k) {
      int i = tid + k * 256;
      op[i] = zb[(i / 12) * 13 + i % 12];
    }
  }
}

extern "C" void kernel_launch(void* const* d_in, const int* in_sizes, int n_in,
                              void* d_out, int out_size, void* d_ws, size_t ws_size,
                              hipStream_t stream) {
  const float* X   = (const float*)d_in[0];
  const int*   ei  = (const int*)d_in[1];
  const float* ew  = (const float*)d_in[2];
  const float* lam = (const float*)d_in[3];
  const float* Wc  = (const float*)d_in[4];
  const float* bc  = (const float*)d_in[5];
  const float* tw  = (const float*)d_in[6];
  const float* tb  = (const float*)d_in[7];
  const float* rw  = (const float*)d_in[8];
  const float* rb  = (const float*)d_in[9];
  const float* lg  = (const float*)d_in[10];
  const float* lb  = (const float*)d_in[11];
  float* out = (float*)d_out;
  float* ws = (float*)d_ws;
  float* x0   = ws + OFF_X0;
  float* tx1  = ws + OFF_TX1;
  float* cheb = ws + OFF_CHEB;
  float* deg  = ws + OFF_DEG;
  float* swv  = ws + OFF_SW;
  int* rowp = (int*)(ws + OFF_ROWP);
  int* cnt  = (int*)(ws + OFF_CNT);
  int* fill = (int*)(ws + OFF_FILL);
  int* ccol = (int*)(ws + OFF_CCOL);
  float* cwv = ws + OFF_CW;
  unsigned short* twt = (unsigned short*)(ws + OFF_TWT);
  unsigned short* rwt = (unsigned short*)(ws + OFF_RWT);
  const int* srcp = ei;
  const int* dstp = ei + EE;

  hipMemsetAsync(deg, 0, (size_t)(OFF_CCOL - OFF_DEG) * sizeof(float), stream);
  k_prep<<<48, 256, 0, stream>>>(tw, rw, twt, rwt);
  k_deg_cnt<<<(EE + 255) / 256, 256, 0, stream>>>(srcp, dstp, ew, deg, cnt);
  k_scan<<<1, 256, 0, stream>>>(deg, lam, cnt, swv, rowp);
  k_fill<<<(EE + 255) / 256, 256, 0, stream>>>(srcp, dstp, ew, lam, rowp, fill, ccol, cwv);
  k_build_x0<<<(NN * NODE_F + 255) / 256, 256, 0, stream>>>(X, x0);
  k_prop1<<<NN, 256, 0, stream>>>(x0, swv, rowp, ccol, cwv, tx1);
  k_cheb<<<NN, 256, 0, stream>>>(x0, tx1, swv, rowp, ccol, cwv, Wc, bc, cheb);
  k_final3<<<1000, 256, 0, stream>>>(X, cheb, twt, rwt, tb, rb, lg, lb, out);
}